// Round 7
// baseline (60.024 us; speedup 1.0000x reference)
//
#include <hip/hip_runtime.h>

#define PRECS 1e-6f

// raw hardware transcendentals: v_exp_f32 / v_log_f32 (base-2).
// fpow(0, e>0) == 0 exactly: log2(0)=-inf -> exp2(-inf)=0.
__device__ __forceinline__ float fpow(float b, float e) {
    return __builtin_amdgcn_exp2f(e * __builtin_amdgcn_logf(b));
}

__device__ __forceinline__ float frcp(float v) {
    return __builtin_amdgcn_rcpf(v);
}

template <int CTRL>
__device__ __forceinline__ float dpp_mov(float v) {
    return __int_as_float(
        __builtin_amdgcn_update_dpp(0, __float_as_int(v), CTRL, 0xF, 0xF, true));
}

// sum over each 8-lane group, entirely on the VALU pipe (DPP, no LDS)
__device__ __forceinline__ float rsum8(float v) {
    v += dpp_mov<0xB1>(v);   // quad_perm [1,0,3,2]  : lane ^= 1
    v += dpp_mov<0x4E>(v);   // quad_perm [2,3,0,1]  : lane ^= 2
    v += dpp_mov<0x141>(v);  // row_half_mirror      : lane -> 7-lane within 8
    return v;
}

// 4-stage wave-specialized pipeline over 16-step blocks (one wave per SIMD):
//   wave 0 (A): W-chain. Carries W separately via the exact identity
//               W' = med3(W+dW, 0, WUM+WLM+capD)  (cascade only discards at
//               the last stage) so the next pow launches ~8cy after dW.
//   wave 1 (B): S-chain, chain-minimal: FR/iFR/g all precomputed by C.
//   wave 2 (C): loader + FR candidate + FR select-scan resolve (pure function
//               of PE/R_per, no S-chain input) -> {FR, iFR, g=oneK*FR_prev}
//   wave 3 (D): QI/QG EMA + 8-lane reductions + stores (reads stB only).
__global__ __launch_bounds__(256, 1) void xaj_kernel(
    const float* __restrict__ x,     // (365, 2000, 3)
    const float* __restrict__ prm,   // (2000, 12, 8)
    float* __restrict__ out)         // (365, 2000, 5)
{
    constexpr int Nstep = 365, Ngrid = 2000;
    constexpr int xstride = Ngrid * 3;
    constexpr int K = 16;            // steps per pipeline block
    constexpr int NBLK = 23;         // 23*16 = 368 padded steps
    constexpr int NPH  = NBLK + 3;   // 26 phases (D drains at p = NBLK+2)

    const int wid  = (int)threadIdx.x >> 6;   // 0=A, 1=B, 2=C, 3=D
    const int lane = (int)threadIdx.x & 63;
    const int g = blockIdx.x * 8 + (lane >> 3);   // 250 blocks * 8 grids = 2000
    const int m = lane & 7;

    __shared__ float2 stIn[2][K][64];   // {P, PET*KE}            (C -> A)
    __shared__ float4 stA[4][K][64];    // {PE, R_per, E, -}      (A -> C,B)
    __shared__ float4 stFR[2][K][64];   // {FR, iFR, g, -}        (C -> B)
    __shared__ float4 stB[2][K][64];    // {RS, FR*Sn, E, -}      (B -> D)

    const float lo[12] = {0.3f,0.0f,0.01f,0.01f,0.01f,0.09f,0.01f,0.0f,0.01f,0.01f,0.0f,0.0f};
    const float hi[12] = {2.0f,5.0f,100.0f,100.0f,200.0f,1.0f,100.0f,10.0f,0.7f,0.7f,0.998f,0.998f};
    float p[12];
    const float* pb = prm + (size_t)g * 96 + m;
#pragma unroll
    for (int i = 0; i < 12; ++i)
        p[i] = lo[i] + pb[i * 8] * (hi[i] - lo[i]);

    const float KE=p[0], B=p[1], WUM=p[2], WLM=p[3], WM=p[4], C=p[5],
                SM=p[6], EX=p[7], KI_=p[8], KG_=p[9], CI=p[10], CG=p[11];

    // loop-invariant derived constants
    const float wdm  = fmaxf(WM - WUM - WLM, 0.f);
    const float sumk = KI_ + KG_;
    const float nrm  = (1.f - PRECS) / (sumk + PRECS);
    const float KI   = (sumk < 1.f) ? KI_ : KI_ * nrm;
    const float KG   = (sumk < 1.f) ? KG_ : KG_ * nrm;
    const float expB = 1.f + B,  invB  = 1.f / expB;
    const float WMM  = WM * expB;
    const float expEX= 1.f + EX, invEX = 1.f / expEX;
    const float SMM  = SM * expEX;
    const float inv_WLM = 1.f / (WLM + PRECS);
    const float inv_WM  = 1.f / (WM  + PRECS);
    const float inv_WMM = 1.f / (WMM + PRECS);
    const float inv_SM  = 1.f / (SM  + PRECS);
    const float inv_SMM = 1.f / (SMM + PRECS);
    const float oneK = 1.f - KI - KG;
    const float omCI = 1.f - CI, omCG = 1.f - CG;
    const float CWLM = C * WLM;
    const float inv1p = 1.f / (1.f + PRECS);
    const float sumUL = WUM + WLM;
    // exact floor of ratio_s when S_eq hits the SM clamp: 1 - SM*inv_SM
    const float eps2  = fmaxf(PRECS, fmaf(-SM, inv_SM, 1.f));

    // -------- per-stage carried state (exclusive per wave path) --------
    float WU = 0.001f, WL = 0.001f, WD = 0.001f;          // A
    float W  = 0.001f + 0.001f + 0.001f;                  // A (early-W carry)
    float Snc = 0.001f / oneK;                            // B: pre-oneK S; step0
                                                          // sf = Snc*(oneK*0.001)
                                                          // == 0.001*0.001 exact-ish
    float FRc = 0.001f, iFRc = frcp(0.001f + PRECS);      // C resolve carry
    float QI = 0.001f, QG = 0.001f;                       // D
    const float cKI = omCI * KI, cKG = omCG * KG;         // D
    const float wa = (m == 0 || m == 1) ? 0.125f : 0.f;   // D output weights
    const float wb = (m == 0 || m == 2) ? 0.125f : 0.f;
    const float wc = (m == 0 || m == 3) ? 0.125f : 0.f;
    const float wd = (m >= 4) ? 0.125f : 0.f;
    const int   col = (m < 4) ? m : 4;
    float* outp = out + (size_t)g * 5 + col;
    const size_t ostr = (size_t)Ngrid * 5;
    const float* xg = x + (size_t)g * 3;
    float Pr[K], Er[K];                                   // C load staging

    // ---------------- stage bodies ----------------
    auto ASTEP = [&](int ibuf, int obuf) {
        float2 rin[K];
#pragma unroll
        for (int k = 0; k < K; ++k)
            rin[k] = stIn[ibuf][k][lane];
#pragma unroll
        for (int k = 0; k < K; ++k) {
            const float Pt = rin[k].x, PET_t = rin[k].y;
            // evap cascade; D = relu(PET-P-WU) is exact
            const float EU = fminf(PET_t, WU + Pt);
            const float D  = fmaxf(PET_t - Pt - WU, 0.f);
            const float we = fmaxf(WL - CWLM, 0.f);
            const float wr = we * frcp(we + 1.f);
            const float cwet = wr * WL * inv_WLM;
            const float ELdry = fminf(C * D, WL);
            const float EL = fminf(fmaxf(fmaf(1.f - wr, ELdry, cwet * D), 0.f), WL);
            const float ED = fminf(C * fmaxf(D - EL, 0.f), WD);
            const float E  = EU + EL + ED;
            const float PE = fmaxf(Pt - E, 0.f);
            // runoff from the CARRIED W (short path to the pow chain);
            // omr = relu(pw1 - PE/WMM), err <= PRECS
            const float base_W = fmaxf(fmaf(-W, inv_WM, 1.f), PRECS);
            const float pw1 = fpow(base_W, invB);
            const float omr = fmaxf(fmaf(-PE, inv_WMM, pw1), 0.f);
            const float R_per = fmaxf(fmaf(WM, fpow(omr, expB), PE + (W - WM)), 0.f);
            const float dW = Pt - E - R_per;
            const float capD = fmaxf(wdm, WD);
            // EXACT: the cascade discards mass only at the final WD clamp,
            // floors only cascade deficits -> W' = med3(W+dW, 0, sumUL+capD)
            W = __builtin_amdgcn_fmed3f(W + dW, 0.f, sumUL + capD);
            // unified signed-residual cascade (exact for both signs of dW)
            const float c0  = WU + dW;
            const float WUn = __builtin_amdgcn_fmed3f(c0, 0.f, WUM);
            const float c1  = WL + (c0 - WUn);
            const float WLn = __builtin_amdgcn_fmed3f(c1, 0.f, WLM);
            const float c2  = WD + (c1 - WLn);
            const float WDn = __builtin_amdgcn_fmed3f(c2, 0.f, capD);
            WU = WUn; WL = WLn; WD = WDn;
            stA[obuf][k][lane] = make_float4(PE, R_per, E, 0.f);
        }
    };

    auto BSTEP = [&](int abuf, int fbuf) {
        float4 ra[K], rg[K];
#pragma unroll
        for (int k = 0; k < K; ++k) ra[k] = stA[abuf][k][lane];
#pragma unroll
        for (int k = 0; k < K; ++k) rg[k] = stFR[fbuf][k][lane];
#pragma unroll
        for (int k = 0; k < K; ++k) {
            const float PE = ra[k].x, R_per = ra[k].y;
            const float FR = rg[k].x, iFR = rg[k].y;
            const float sf = Snc * rg[k].z;          // = S_prev * FR_prev
            const float S_eq = fminf(sf * iFR, SM);
            const float ratio_s = fmaxf(fmaf(-(sf * inv_SM), iFR, 1.f), eps2);
            const float u   = fpow(ratio_s, invEX);
            const float om2 = fmaxf(fmaf(-PE, inv_SMM, u), 0.f);
            const float base = (PE - SM) + S_eq;
            float RS = fmaf(SM, fpow(om2, expEX), base) * FR;
            RS = __builtin_amdgcn_fmed3f(RS, 0.f, R_per);
            Snc = fminf(fmaf(R_per - RS, iFR, S_eq), SM);   // pre-oneK S
            stB[fbuf][k][lane] = make_float4(RS, FR * Snc, ra[k].z, 0.f);
        }
    };

    auto CISSUE = [&](int blk) {
#pragma unroll
        for (int k = 0; k < K; ++k) {
            int t = blk * K + k;
            t = (t < Nstep) ? t : Nstep - 1;
            const float* xq = xg + (size_t)t * xstride;
            Pr[k] = xq[0];
            Er[k] = xq[2];
        }
    };
    auto CFR = [&](int abuf, int fbuf) {
        // candidates + select-scan resolve (pure function of PE/R_per):
        // rcp(min(aa,1)+PRECS) == max(rcp(aa+PRECS), inv1p)
#pragma unroll
        for (int k = 0; k < K; ++k) {
            const float4 ra = stA[abuf][k][lane];
            const float gk = oneK * FRc;             // g for step k: oneK*FR_{k-1}
            const float q  = frcp(ra.x + PRECS);
            const float aa = ra.y * q;
            const float FRn  = fminf(aa, 1.f);
            const float iFRn = fmaxf(frcp(aa + PRECS), inv1p);
            const bool wet = ra.x > 0.f;
            FRc  = wet ? FRn  : FRc;
            iFRc = wet ? iFRn : iFRc;
            stFR[fbuf][k][lane] = make_float4(FRc, iFRc, gk, 0.f);
        }
    };
    auto CWRITE = [&](int buf) {
#pragma unroll
        for (int k = 0; k < K; ++k)
            stIn[buf][k][lane] = make_float2(Pr[k], Er[k] * KE);
    };

    auto DSTEP = [&](int bbuf, int blk) {
        float4 rb[K];
#pragma unroll
        for (int k = 0; k < K; ++k) rb[k] = stB[bbuf][k][lane];
        const int t0 = blk * K;
#pragma unroll
        for (int k = 0; k < K; ++k) {
            // QI/QG EMA: RI = KI*FR*Sn = KI*rb.y, RG = KG*rb.y
            QI = fmaf(CI, QI, cKI * rb[k].y);
            QG = fmaf(CG, QG, cKG * rb[k].y);
            const float u0 = rsum8(rb[k].x);
            const float u1 = rsum8(QI);
            const float u2 = rsum8(QG);
            const float u3 = rsum8(rb[k].z);
            const float v = fmaf(u0, wa, fmaf(u1, wb, fmaf(u2, wc, u3 * wd)));
            if (t0 + k < Nstep)
                outp[(size_t)(t0 + k) * ostr] = v;
        }
    };

    // ---------------- phase loop ----------------
    // phase p (0..25):
    //   A: block p        (p < NBLK):      stIn[p&1] -> stA[p&3]
    //   B: block p-2      (2<=p<NBLK+2):   stA[(p-2)&3] + stFR[(p-2)&1] -> stB[(p-2)&1]
    //   C: load block p+1 (p+1 < NBLK) -> stIn[(p+1)&1];
    //      FR block p-1   (1<=p<NBLK+1):   stA[(p-1)&3] -> stFR[(p-1)&1]
    //   D: block p-3      (p>=3):          stB[(p-3)&1] -> out
    if (wid == 2) { CISSUE(0); CWRITE(0); }   // prime block 0
    __syncthreads();

#pragma unroll 1
    for (int ph = 0; ph < NPH; ++ph) {
        if (wid == 0) {
            if (ph < NBLK) ASTEP(ph & 1, ph & 3);
        } else if (wid == 1) {
            if (ph >= 2 && ph < NBLK + 2) BSTEP((ph - 2) & 3, (ph - 2) & 1);
        } else if (wid == 2) {
            const bool ld = (ph + 1 < NBLK);
            if (ld) CISSUE(ph + 1);                       // issue loads first...
            if (ph >= 1 && ph < NBLK + 1)
                CFR((ph - 1) & 3, (ph - 1) & 1);          // ...hide latency under FR
            if (ld) CWRITE((ph + 1) & 1);
        } else {
            if (ph >= 3) DSTEP((ph - 3) & 1, ph - 3);
        }
        __syncthreads();
    }
}

extern "C" void kernel_launch(void* const* d_in, const int* in_sizes, int n_in,
                              void* d_out, int out_size, void* d_ws, size_t ws_size,
                              hipStream_t stream) {
    const float* x   = (const float*)d_in[0];
    const float* prm = (const float*)d_in[1];
    float* out = (float*)d_out;
    xaj_kernel<<<250, 256, 0, stream>>>(x, prm, out);
}

// Round 8
// 57.523 us; speedup vs baseline: 1.0435x; 1.0435x over previous
//
#include <hip/hip_runtime.h>

#define PRECS 1e-6f

// raw hardware transcendentals: v_exp_f32 / v_log_f32 (base-2).
// fpow(0, e>0) == 0 exactly: log2(0)=-inf -> exp2(-inf)=0.
__device__ __forceinline__ float fpow(float b, float e) {
    return __builtin_amdgcn_exp2f(e * __builtin_amdgcn_logf(b));
}

__device__ __forceinline__ float frcp(float v) {
    return __builtin_amdgcn_rcpf(v);
}

__device__ __forceinline__ float med3(float a, float b, float c) {
    return __builtin_amdgcn_fmed3f(a, b, c);
}

template <int CTRL>
__device__ __forceinline__ float dpp_mov(float v) {
    return __int_as_float(
        __builtin_amdgcn_update_dpp(0, __float_as_int(v), CTRL, 0xF, 0xF, true));
}

// sum over each 8-lane group, entirely on the VALU pipe (DPP, no LDS)
__device__ __forceinline__ float rsum8(float v) {
    v += dpp_mov<0xB1>(v);   // quad_perm [1,0,3,2]  : lane ^= 1
    v += dpp_mov<0x4E>(v);   // quad_perm [2,3,0,1]  : lane ^= 2
    v += dpp_mov<0x141>(v);  // row_half_mirror      : lane -> 7-lane within 8
    return v;
}

// 4-stage wave-specialized pipeline over 16-step blocks (one wave per SIMD).
// This revision minimizes stage A's per-step DEPENDENT chain:
//   - T0 = P-EU collapses to -min(PET-P, WU); PE = relu(-(M0+EL+ED))
//   - EL in division form (we*ELwet + ELdry)*rcp(1+we), with we / rcp(1+we) /
//     WL*inv_WLM hoisted to the previous step's tail (off-chain)
//   - min(max(x,0),cap) = med3(x,0,cap) contractions for EL/ED
//   - c0 = (WU-SUME) - R_per puts the pow result one hop from the cascade
//   - pw1 = pow(base_W) and (W-WM) hoisted via the carried-W identity
__global__ __launch_bounds__(256, 1) void xaj_kernel(
    const float* __restrict__ x,     // (365, 2000, 3)
    const float* __restrict__ prm,   // (2000, 12, 8)
    float* __restrict__ out)         // (365, 2000, 5)
{
    constexpr int Nstep = 365, Ngrid = 2000;
    constexpr int xstride = Ngrid * 3;
    constexpr int K = 16;            // steps per pipeline block
    constexpr int NBLK = 23;         // 23*16 = 368 padded steps
    constexpr int NPH  = NBLK + 3;   // 26 phases (D drains at p = NBLK+2)

    const int wid  = (int)threadIdx.x >> 6;   // 0=A, 1=B, 2=C, 3=D
    const int lane = (int)threadIdx.x & 63;
    const int g = blockIdx.x * 8 + (lane >> 3);   // 250 blocks * 8 grids = 2000
    const int m = lane & 7;

    __shared__ float2 stIn[2][K][64];   // {P, PET*KE}            (C -> A)
    __shared__ float4 stA[4][K][64];    // {PE, R_per, E, -}      (A -> C,B)
    __shared__ float4 stFR[2][K][64];   // {FR, iFR, g, -}        (C -> B)
    __shared__ float4 stB[2][K][64];    // {RS, FR*Sn, E, -}      (B -> D)

    const float lo[12] = {0.3f,0.0f,0.01f,0.01f,0.01f,0.09f,0.01f,0.0f,0.01f,0.01f,0.0f,0.0f};
    const float hi[12] = {2.0f,5.0f,100.0f,100.0f,200.0f,1.0f,100.0f,10.0f,0.7f,0.7f,0.998f,0.998f};
    float p[12];
    const float* pb = prm + (size_t)g * 96 + m;
#pragma unroll
    for (int i = 0; i < 12; ++i)
        p[i] = lo[i] + pb[i * 8] * (hi[i] - lo[i]);

    const float KE=p[0], B=p[1], WUM=p[2], WLM=p[3], WM=p[4], C=p[5],
                SM=p[6], EX=p[7], KI_=p[8], KG_=p[9], CI=p[10], CG=p[11];

    // loop-invariant derived constants
    const float wdm  = fmaxf(WM - WUM - WLM, 0.f);
    const float sumk = KI_ + KG_;
    const float nrm  = (1.f - PRECS) / (sumk + PRECS);
    const float KI   = (sumk < 1.f) ? KI_ : KI_ * nrm;
    const float KG   = (sumk < 1.f) ? KG_ : KG_ * nrm;
    const float expB = 1.f + B,  invB  = 1.f / expB;
    const float WMM  = WM * expB;
    const float expEX= 1.f + EX, invEX = 1.f / expEX;
    const float SMM  = SM * expEX;
    const float inv_WLM = 1.f / (WLM + PRECS);
    const float inv_WM  = 1.f / (WM  + PRECS);
    const float inv_WMM = 1.f / (WMM + PRECS);
    const float inv_SM  = 1.f / (SM  + PRECS);
    const float inv_SMM = 1.f / (SMM + PRECS);
    const float oneK = 1.f - KI - KG;
    const float omCI = 1.f - CI, omCG = 1.f - CG;
    const float CWLM = C * WLM;
    const float inv1p = 1.f / (1.f + PRECS);
    const float sumUL = WUM + WLM;
    // exact floor of ratio_s when S_eq hits the SM clamp: 1 - SM*inv_SM
    const float eps2  = fmaxf(PRECS, fmaf(-SM, inv_SM, 1.f));

    // -------- per-stage carried state (exclusive per wave path) --------
    float WU = 0.001f, WL = 0.001f, WD = 0.001f;          // A
    float W  = 0.001f + 0.001f + 0.001f;                  // A (early-W carry)
    // A: hoisted step-tail values (functions of carried WL / W only)
    float weC    = fmaxf(WL - CWLM, 0.f);
    float rC     = frcp(1.f + weC);
    float wlinvC = WL * inv_WLM;
    float WmWM   = W - WM;
    float pw1C   = fpow(fmaxf(fmaf(-W, inv_WM, 1.f), PRECS), invB);

    float Snc = 0.001f / oneK;                            // B: pre-oneK S
    float FRc = 0.001f, iFRc = frcp(0.001f + PRECS);      // C resolve carry
    float QI = 0.001f, QG = 0.001f;                       // D
    const float cKI = omCI * KI, cKG = omCG * KG;         // D
    const float wa = (m == 0 || m == 1) ? 0.125f : 0.f;   // D output weights
    const float wb = (m == 0 || m == 2) ? 0.125f : 0.f;
    const float wc = (m == 0 || m == 3) ? 0.125f : 0.f;
    const float wd = (m >= 4) ? 0.125f : 0.f;
    const int   col = (m < 4) ? m : 4;
    float* outp = out + (size_t)g * 5 + col;
    const size_t ostr = (size_t)Ngrid * 5;
    const float* xg = x + (size_t)g * 3;
    float Pr[K], Er[K];                                   // C load staging

    // ---------------- stage bodies ----------------
    auto ASTEP = [&](int ibuf, int obuf) {
        float2 rin[K];
#pragma unroll
        for (int k = 0; k < K; ++k)
            rin[k] = stIn[ibuf][k][lane];
#pragma unroll
        for (int k = 0; k < K; ++k) {
            const float Pt = rin[k].x, PET_t = rin[k].y;
            const float PETmP = PET_t - Pt;              // input-only, off-chain
            // M0 = min(PET-P, WU) = P - EU  (EU = P + M0)
            const float M0 = fminf(PETmP, WU);
            const float D  = fmaxf(PETmP - WU, 0.f);
            // EL division form: (we*ELwet + ELdry) * rcp(1+we), hoisted we/r/wlinv
            const float ELwet = D * wlinvC;
            const float CD    = C * D;
            const float ELdry = fminf(CD, WL);
            const float num   = fmaf(weC, ELwet, ELdry);
            const float EL    = med3(num * rC, 0.f, WL);
            const float ED    = med3(fmaf(-C, EL, CD), 0.f, WD);
            // SUME = E - P;  PE = relu(-SUME);  E = P + SUME (stash only)
            const float SUME = (M0 + EL) + ED;
            const float PE   = fmaxf(-SUME, 0.f);
            const float E    = Pt + SUME;
            // runoff; omr = relu(pw1 - PE/WMM), err <= PRECS
            const float omr  = fmaxf(fmaf(-PE, inv_WMM, pw1C), 0.f);
            const float powr = fpow(omr, expB);
            const float PEpW = PE + WmWM;
            const float R_per = fmaxf(fmaf(WM, powr, PEpW), 0.f);
            // cascade: c0 = WU + dW = (WU - SUME) - R_per
            const float WUmS = WU - SUME;
            const float WmS  = W - SUME;
            const float c0   = WUmS - R_per;
            const float capD = fmaxf(wdm, WD);
            // EXACT: cascade discards only at the last stage ->
            // W' = med3(W+dW, 0, sumUL+capD)
            W = med3(WmS - R_per, 0.f, sumUL + capD);
            const float WUn = med3(c0, 0.f, WUM);
            const float c1  = WL + (c0 - WUn);
            const float WLn = med3(c1, 0.f, WLM);
            const float c2  = WD + (c1 - WLn);
            const float WDn = med3(c2, 0.f, capD);
            WU = WUn; WL = WLn; WD = WDn;
            // step-tail hoists for the next step (off next step's chain)
            weC    = fmaxf(WLn - CWLM, 0.f);
            rC     = frcp(1.f + weC);
            wlinvC = WLn * inv_WLM;
            WmWM   = W - WM;
            pw1C   = fpow(fmaxf(fmaf(-W, inv_WM, 1.f), PRECS), invB);
            stA[obuf][k][lane] = make_float4(PE, R_per, E, 0.f);
        }
    };

    auto BSTEP = [&](int abuf, int fbuf) {
        float4 ra[K], rg[K];
#pragma unroll
        for (int k = 0; k < K; ++k) ra[k] = stA[abuf][k][lane];
#pragma unroll
        for (int k = 0; k < K; ++k) rg[k] = stFR[fbuf][k][lane];
#pragma unroll
        for (int k = 0; k < K; ++k) {
            const float PE = ra[k].x, R_per = ra[k].y;
            const float FR = rg[k].x, iFR = rg[k].y;
            const float sf = Snc * rg[k].z;          // = S_prev * FR_prev
            const float S_eq = fminf(sf * iFR, SM);
            const float ratio_s = fmaxf(fmaf(-(sf * inv_SM), iFR, 1.f), eps2);
            const float u   = fpow(ratio_s, invEX);
            const float om2 = fmaxf(fmaf(-PE, inv_SMM, u), 0.f);
            const float base = (PE - SM) + S_eq;
            float RS = fmaf(SM, fpow(om2, expEX), base) * FR;
            RS = med3(RS, 0.f, R_per);
            Snc = fminf(fmaf(R_per - RS, iFR, S_eq), SM);   // pre-oneK S
            stB[fbuf][k][lane] = make_float4(RS, FR * Snc, ra[k].z, 0.f);
        }
    };

    auto CISSUE = [&](int blk) {
#pragma unroll
        for (int k = 0; k < K; ++k) {
            int t = blk * K + k;
            t = (t < Nstep) ? t : Nstep - 1;
            const float* xq = xg + (size_t)t * xstride;
            Pr[k] = xq[0];
            Er[k] = xq[2];
        }
    };
    auto CFR = [&](int abuf, int fbuf) {
        // candidates + select-scan resolve (pure function of PE/R_per):
        // rcp(min(aa,1)+PRECS) == max(rcp(aa+PRECS), inv1p)
#pragma unroll
        for (int k = 0; k < K; ++k) {
            const float4 ra = stA[abuf][k][lane];
            const float gk = oneK * FRc;             // g for step k: oneK*FR_{k-1}
            const float q  = frcp(ra.x + PRECS);
            const float aa = ra.y * q;
            const float FRn  = fminf(aa, 1.f);
            const float iFRn = fmaxf(frcp(aa + PRECS), inv1p);
            const bool wet = ra.x > 0.f;
            FRc  = wet ? FRn  : FRc;
            iFRc = wet ? iFRn : iFRc;
            stFR[fbuf][k][lane] = make_float4(FRc, iFRc, gk, 0.f);
        }
    };
    auto CWRITE = [&](int buf) {
#pragma unroll
        for (int k = 0; k < K; ++k)
            stIn[buf][k][lane] = make_float2(Pr[k], Er[k] * KE);
    };

    auto DSTEP = [&](int bbuf, int blk) {
        float4 rb[K];
#pragma unroll
        for (int k = 0; k < K; ++k) rb[k] = stB[bbuf][k][lane];
        const int t0 = blk * K;
#pragma unroll
        for (int k = 0; k < K; ++k) {
            // QI/QG EMA: RI = KI*FR*Sn = KI*rb.y, RG = KG*rb.y
            QI = fmaf(CI, QI, cKI * rb[k].y);
            QG = fmaf(CG, QG, cKG * rb[k].y);
            const float u0 = rsum8(rb[k].x);
            const float u1 = rsum8(QI);
            const float u2 = rsum8(QG);
            const float u3 = rsum8(rb[k].z);
            const float v = fmaf(u0, wa, fmaf(u1, wb, fmaf(u2, wc, u3 * wd)));
            if (t0 + k < Nstep)
                outp[(size_t)(t0 + k) * ostr] = v;
        }
    };

    // ---------------- phase loop ----------------
    // phase p (0..25):
    //   A: block p        (p < NBLK):      stIn[p&1] -> stA[p&3]
    //   B: block p-2      (2<=p<NBLK+2):   stA[(p-2)&3] + stFR[(p-2)&1] -> stB[(p-2)&1]
    //   C: load block p+1 (p+1 < NBLK) -> stIn[(p+1)&1];
    //      FR block p-1   (1<=p<NBLK+1):   stA[(p-1)&3] -> stFR[(p-1)&1]
    //   D: block p-3      (p>=3):          stB[(p-3)&1] -> out
    if (wid == 2) { CISSUE(0); CWRITE(0); }   // prime block 0
    __syncthreads();

#pragma unroll 1
    for (int ph = 0; ph < NPH; ++ph) {
        if (wid == 0) {
            if (ph < NBLK) ASTEP(ph & 1, ph & 3);
        } else if (wid == 1) {
            if (ph >= 2 && ph < NBLK + 2) BSTEP((ph - 2) & 3, (ph - 2) & 1);
        } else if (wid == 2) {
            const bool ld = (ph + 1 < NBLK);
            if (ld) CISSUE(ph + 1);                       // issue loads first...
            if (ph >= 1 && ph < NBLK + 1)
                CFR((ph - 1) & 3, (ph - 1) & 1);          // ...hide latency under FR
            if (ld) CWRITE((ph + 1) & 1);
        } else {
            if (ph >= 3) DSTEP((ph - 3) & 1, ph - 3);
        }
        __syncthreads();
    }
}

extern "C" void kernel_launch(void* const* d_in, const int* in_sizes, int n_in,
                              void* d_out, int out_size, void* d_ws, size_t ws_size,
                              hipStream_t stream) {
    const float* x   = (const float*)d_in[0];
    const float* prm = (const float*)d_in[1];
    float* out = (float*)d_out;
    xaj_kernel<<<250, 256, 0, stream>>>(x, prm, out);
}